// Round 3
// baseline (407.647 us; speedup 1.0000x reference)
//
#include <hip/hip_runtime.h>
#include <hip/hip_bf16.h>
#include <math.h>

// Gate: logits = x @ W^T ; scores = sigmoid(logits)+bias ; top-8 ; normalize *2.5
// T=16384, H=K=4096, E=256.
// fp32 GEMM via EXACT 3-way bf16 truncation split (x = h1+h2+h3 bit-exact),
// 6 cross products (11,12,21,22,13,31) -> rel error ~2^-24, fp32 MFMA accum.
// One block = 64 tokens x ALL 256 experts -> fused in-block top-k epilogue.

using bf16x4 = __attribute__((ext_vector_type(4))) short;
using bf16x8 = __attribute__((ext_vector_type(8))) short;
using f32x4  = __attribute__((ext_vector_type(4))) float;

constexpr int E_EXPERTS = 256;
constexpr int KDIM      = 4096;
constexpr int TOPK      = 8;
constexpr float SCALE   = 2.5f;

constexpr int BM = 64, BK = 32, NT = 512;
constexpr int NSTEP = KDIM / BK;      // 128
constexpr int BUFS  = 30720;          // shorts per LDS buffer (60 KiB)
// Buffer layout (short offsets), k-group-major with row swizzle pr = r ^ (2g):
//   A level lev (2048 sh): lev*2048 + g*512  + (r^(2g))*8   (+h*4 for 8B halves)
//   B level lev (8192 sh): 6144 + lev*8192 + g*2048 + (e^(2g))*8

__device__ __forceinline__ void load_lds16(const short* g, short* l) {
    auto gp = (const __attribute__((address_space(1))) short*)g;
    auto lp = (__attribute__((address_space(3))) short*)(uintptr_t)l;
    __builtin_amdgcn_global_load_lds(gp, lp, 16, 0, 0);
}

// Exact truncation split: x == bf16(h1)+bf16(h2)+bf16(h3) (normal fp32, ~2^-32 tail).
__device__ __forceinline__ void split1(float x, short& h1, short& h2, short& h3) {
    unsigned u = __float_as_uint(x);
    h1 = (short)(u >> 16);
    float r1 = x - __uint_as_float(u & 0xFFFF0000u);
    unsigned u1 = __float_as_uint(r1);
    h2 = (short)(u1 >> 16);
    float r2 = r1 - __uint_as_float(u1 & 0xFFFF0000u);
    h3 = (short)(__float_as_uint(r2) >> 16);
}

__global__ void wsplit_kernel(const float* __restrict__ W, short* __restrict__ W1,
                              short* __restrict__ W2, short* __restrict__ W3) {
    int i = blockIdx.x * 256 + threadIdx.x;   // float4 index
    float4 w = ((const float4*)W)[i];
    bf16x4 s1, s2, s3;
    short a, b, c;
    split1(w.x, a, b, c); s1.x = a; s2.x = b; s3.x = c;
    split1(w.y, a, b, c); s1.y = a; s2.y = b; s3.y = c;
    split1(w.z, a, b, c); s1.z = a; s2.z = b; s3.z = c;
    split1(w.w, a, b, c); s1.w = a; s2.w = b; s3.w = c;
    ((bf16x4*)W1)[i] = s1;
    ((bf16x4*)W2)[i] = s2;
    ((bf16x4*)W3)[i] = s3;
}

__global__ __launch_bounds__(NT, 2) void gate_fused(
    const float* __restrict__ X,
    const short* __restrict__ W1, const short* __restrict__ W2, const short* __restrict__ W3,
    const float* __restrict__ Bias,
    float* __restrict__ outIdx, float* __restrict__ outW) {
    __shared__ short lds[2 * BUFS];   // 120 KiB

    const int tid  = threadIdx.x;
    const int lane = tid & 63;
    const int w    = tid >> 6;        // wave 0..7
    const int wm   = w >> 2;          // 0..1 : 32-token half
    const int wn   = w & 3;           // 0..3 : 64-expert quarter
    const int tok0 = blockIdx.x * BM;

    // ---- A staging geometry: thread owns float4 (row ar, k-chunk aq)
    const int ar = tid >> 3;          // 0..63
    const int aq = tid & 7;           // 0..7 (4 floats each)
    const int ag = aq >> 1, ah = aq & 1;
    const float* xp = X + (size_t)(tok0 + ar) * KDIM + aq * 4;
    const int aoff = (ag << 9) + ((ar ^ (ag << 1)) << 3) + (ah << 2);  // within A level

    // ---- B staging geometry: two 16B chunks per thread per level
    const short* wl0 = W1; const short* wl1 = W2; const short* wl2 = W3;
    int brow[2], bg[2];
    {
        int c0 = tid;        bg[0] = c0 >> 8; brow[0] = (c0 & 255) ^ (bg[0] << 1);
        int c1 = 512 + tid;  bg[1] = c1 >> 8; brow[1] = (c1 & 255) ^ (bg[1] << 1);
    }

    // ---- compute-side LDS offsets (shorts)
    const int g = lane >> 4;
    int aro[2], bro[4];
#pragma unroll
    for (int mf = 0; mf < 2; ++mf) {
        int r = wm * 32 + mf * 16 + (lane & 15);
        aro[mf] = (g << 9) + ((r ^ (g << 1)) << 3);
    }
#pragma unroll
    for (int nf = 0; nf < 4; ++nf) {
        int e = wn * 64 + nf * 16 + (lane & 15);
        bro[nf] = (g << 11) + ((e ^ (g << 1)) << 3);
    }

    auto stageB = [&](short* buf, int k0) {
#pragma unroll
        for (int lev = 0; lev < 3; ++lev) {
            const short* src = (lev == 0) ? wl0 : ((lev == 1) ? wl1 : wl2);
            short* dst = buf + 6144 + lev * 8192;
            load_lds16(src + (size_t)brow[0] * KDIM + k0 + (bg[0] << 3), dst + (size_t)tid * 8);
            load_lds16(src + (size_t)brow[1] * KDIM + k0 + (bg[1] << 3), dst + (size_t)(512 + tid) * 8);
        }
    };

    auto writeA = [&](short* buf, float4 a) {
        bf16x4 s1, s2, s3;
        short h1, h2, h3;
        split1(a.x, h1, h2, h3); s1.x = h1; s2.x = h2; s3.x = h3;
        split1(a.y, h1, h2, h3); s1.y = h1; s2.y = h2; s3.y = h3;
        split1(a.z, h1, h2, h3); s1.z = h1; s2.z = h2; s3.z = h3;
        split1(a.w, h1, h2, h3); s1.w = h1; s2.w = h2; s3.w = h3;
        *(bf16x4*)&buf[0 * 2048 + aoff] = s1;
        *(bf16x4*)&buf[1 * 2048 + aoff] = s2;
        *(bf16x4*)&buf[2 * 2048 + aoff] = s3;
    };

    f32x4 acc[2][4];
#pragma unroll
    for (int i = 0; i < 2; ++i)
#pragma unroll
        for (int j = 0; j < 4; ++j) acc[i][j] = f32x4{0.f, 0.f, 0.f, 0.f};

    auto compute = [&](const short* buf) {
        bf16x8 af[2][3], bfr[4][3];
#pragma unroll
        for (int mf = 0; mf < 2; ++mf)
#pragma unroll
            for (int lev = 0; lev < 3; ++lev)
                af[mf][lev] = *(const bf16x8*)&buf[lev * 2048 + aro[mf]];
#pragma unroll
        for (int nf = 0; nf < 4; ++nf)
#pragma unroll
            for (int lev = 0; lev < 3; ++lev)
                bfr[nf][lev] = *(const bf16x8*)&buf[6144 + lev * 8192 + bro[nf]];
#pragma unroll
        for (int mf = 0; mf < 2; ++mf)
#pragma unroll
            for (int nf = 0; nf < 4; ++nf) {
                f32x4 c = acc[mf][nf];
                c = __builtin_amdgcn_mfma_f32_16x16x32_bf16(af[mf][0], bfr[nf][0], c, 0, 0, 0);
                c = __builtin_amdgcn_mfma_f32_16x16x32_bf16(af[mf][0], bfr[nf][1], c, 0, 0, 0);
                c = __builtin_amdgcn_mfma_f32_16x16x32_bf16(af[mf][1], bfr[nf][0], c, 0, 0, 0);
                c = __builtin_amdgcn_mfma_f32_16x16x32_bf16(af[mf][1], bfr[nf][1], c, 0, 0, 0);
                c = __builtin_amdgcn_mfma_f32_16x16x32_bf16(af[mf][0], bfr[nf][2], c, 0, 0, 0);
                c = __builtin_amdgcn_mfma_f32_16x16x32_bf16(af[mf][2], bfr[nf][0], c, 0, 0, 0);
                acc[mf][nf] = c;
            }
    };

    // ---- prologue: stage step 0 into buffer 0
    stageB(lds, 0);
    writeA(lds, *(const float4*)xp);
    __syncthreads();

    // ---- main loop: compute(buf) while prefetching step ks+1 into buf^1
    int buf = 0;
    for (int ks = 0; ks < NSTEP - 1; ++ks) {
        short* cur = lds + buf * BUFS;
        short* nxt = lds + (buf ^ 1) * BUFS;
        float4 an = *(const float4*)(xp + (size_t)(ks + 1) * BK);  // A prefetch -> regs
        stageB(nxt, (ks + 1) * BK);                                // B prefetch -> LDS
        compute(cur);
        writeA(nxt, an);          // vmcnt(a) long since satisfied; 3 ds_write_b64
        __syncthreads();          // drains B loads (issued one compute phase ago)
        buf ^= 1;
    }
    compute(lds + buf * BUFS);
    __syncthreads();              // all waves done reading LDS before reuse

    // ---- epilogue 1: sigmoid + bias -> LDS score tile [64][260] f32 (padded)
    float* Sl = (float*)lds;
#pragma unroll
    for (int mf = 0; mf < 2; ++mf)
#pragma unroll
        for (int nf = 0; nf < 4; ++nf) {
            const int ec = wn * 64 + nf * 16 + (lane & 15);
            const float bv = Bias[ec];
#pragma unroll
            for (int v = 0; v < 4; ++v) {
                const int tr = wm * 32 + mf * 16 + (lane >> 4) * 4 + v;
                Sl[tr * 260 + ec] = 1.0f / (1.0f + expf(-acc[mf][nf][v])) + bv;
            }
        }
    __syncthreads();

    // ---- epilogue 2: per-wave top-8 for 8 tokens each (butterfly argmax)
    for (int tt = w * 8; tt < w * 8 + 8; ++tt) {
        float v[4];
        int   idx[4];
#pragma unroll
        for (int j = 0; j < 4; ++j) {
            idx[j] = lane + 64 * j;
            v[j]   = Sl[tt * 260 + idx[j]];
        }
        float tv[TOPK];
        int   ti[TOPK];
#pragma unroll
        for (int k = 0; k < TOPK; ++k) {
            float bv = v[0];
            int   bi = idx[0];
#pragma unroll
            for (int j = 1; j < 4; ++j)
                if (v[j] > bv) { bv = v[j]; bi = idx[j]; }     // strict >: lowest idx on tie
#pragma unroll
            for (int off = 1; off < 64; off <<= 1) {
                float ov = __shfl_xor(bv, off);
                int   oi = __shfl_xor(bi, off);
                if (ov > bv || (ov == bv && oi < bi)) { bv = ov; bi = oi; }
            }
            tv[k] = bv;
            ti[k] = bi;
#pragma unroll
            for (int j = 0; j < 4; ++j)
                if (idx[j] == bi) v[j] = -INFINITY;
        }
        float denom = 0.0f;
#pragma unroll
        for (int k = 0; k < TOPK; ++k) denom += tv[k];
        denom += 1e-20f;
#pragma unroll
        for (int k = 0; k < TOPK; ++k) {
            if (lane == k) {
                outIdx[(size_t)(tok0 + tt) * TOPK + k] = (float)ti[k];
                outW[(size_t)(tok0 + tt) * TOPK + k]   = (tv[k] / denom) * SCALE;
            }
        }
    }
}

extern "C" void kernel_launch(void* const* d_in, const int* in_sizes, int n_in,
                              void* d_out, int out_size, void* d_ws, size_t ws_size,
                              hipStream_t stream) {
    const float* x    = (const float*)d_in[0];
    const float* w    = (const float*)d_in[1];
    const float* bias = (const float*)d_in[2];

    const int T = in_sizes[0] / KDIM;   // 16384

    short* W1 = (short*)d_ws;                        // 3 x 2 MiB bf16 split of W
    short* W2 = W1 + (size_t)E_EXPERTS * KDIM;
    short* W3 = W2 + (size_t)E_EXPERTS * KDIM;

    float* outIdx = (float*)d_out;                   // idx chunk (as float values)
    float* outW   = outIdx + (size_t)T * TOPK;       // weight chunk

    wsplit_kernel<<<(E_EXPERTS * KDIM / 4) / 256, 256, 0, stream>>>(w, W1, W2, W3);
    gate_fused<<<T / BM, NT, 0, stream>>>(x, W1, W2, W3, bias, outIdx, outW);
}

// Round 4
// 292.919 us; speedup vs baseline: 1.3917x; 1.3917x over previous
//
#include <hip/hip_runtime.h>
#include <hip/hip_bf16.h>
#include <math.h>

// Gate: logits = x @ W^T ; scores = sigmoid(logits)+bias ; top-8 ; normalize *2.5
// T=16384, H=K=4096, E=256.
// fp32 GEMM via EXACT 3-way bf16 truncation split (x = h1+h2+h3 bit-exact),
// 6 cross products (11,12,21,22,13,31) -> rel error ~2^-24, fp32 MFMA accum.
// Round 4: BM64/BN128/BK32, NT=256, double-buffered LDS (72 KiB) -> 2 blocks/CU
// (cross-block barrier overlap, m114) + one-step-ahead prefetch.

using bf16x4 = __attribute__((ext_vector_type(4))) short;
using bf16x8 = __attribute__((ext_vector_type(8))) short;
using f32x4  = __attribute__((ext_vector_type(4))) float;

constexpr int E_EXPERTS = 256;
constexpr int KDIM      = 4096;
constexpr int TOPK      = 8;
constexpr float SCALE   = 2.5f;

constexpr int BM = 64, BN = 128, BK = 32, NT = 256;
constexpr int NSTEP = KDIM / BK;      // 128
constexpr int BUFS  = 18432;          // shorts per buffer (36 KiB)
// Buffer layout (short offsets), k-group-major (g = 8-bf16 k-chunk, 0..3),
// row-swizzled pr = r ^ (2g)  (measured 0 bank conflicts in R3):
//   A level lev (2048 sh): lev*2048 + g*512  + ((r ^ (2g)) & 63)*8
//   B level lev (4096 sh): 6144 + lev*4096 + g*1024 + ((e ^ (2g)) & 127)*8

__device__ __forceinline__ void load_lds16(const short* g, short* l) {
    auto gp = (const __attribute__((address_space(1))) short*)g;
    auto lp = (__attribute__((address_space(3))) short*)(uintptr_t)l;
    __builtin_amdgcn_global_load_lds(gp, lp, 16, 0, 0);
}

// Exact truncation split: x == bf16(h1)+bf16(h2)+bf16(h3) (normal fp32).
__device__ __forceinline__ void split1(float x, short& h1, short& h2, short& h3) {
    unsigned u = __float_as_uint(x);
    h1 = (short)(u >> 16);
    float r1 = x - __uint_as_float(u & 0xFFFF0000u);
    unsigned u1 = __float_as_uint(r1);
    h2 = (short)(u1 >> 16);
    float r2 = r1 - __uint_as_float(u1 & 0xFFFF0000u);
    h3 = (short)(__float_as_uint(r2) >> 16);
}

__global__ void wsplit_kernel(const float* __restrict__ W, short* __restrict__ W1,
                              short* __restrict__ W2, short* __restrict__ W3) {
    int i = blockIdx.x * 256 + threadIdx.x;   // float4 index
    float4 w = ((const float4*)W)[i];
    bf16x4 s1, s2, s3;
    short a, b, c;
    split1(w.x, a, b, c); s1.x = a; s2.x = b; s3.x = c;
    split1(w.y, a, b, c); s1.y = a; s2.y = b; s3.y = c;
    split1(w.z, a, b, c); s1.z = a; s2.z = b; s3.z = c;
    split1(w.w, a, b, c); s1.w = a; s2.w = b; s3.w = c;
    ((bf16x4*)W1)[i] = s1;
    ((bf16x4*)W2)[i] = s2;
    ((bf16x4*)W3)[i] = s3;
}

__global__ __launch_bounds__(NT, 2) void gate_gemm(
    const float* __restrict__ X,
    const short* __restrict__ W1, const short* __restrict__ W2, const short* __restrict__ W3,
    const float* __restrict__ Bias, float* __restrict__ S) {
    __shared__ short lds[2 * BUFS];   // 72 KiB -> 2 blocks/CU

    const int tid  = threadIdx.x;
    const int lane = tid & 63;
    const int w    = tid >> 6;        // wave 0..3
    const int wm   = w >> 1;          // 0..1 : 32-token half
    const int wn   = w & 1;           // 0..1 : 64-expert half

    // XCD swizzle: 64 consecutive logical ids per XCD; the two expert-halves
    // of each token tile are logically adjacent -> same XCD -> X L2-reuse.
    const int p       = blockIdx.x;
    const int cpx     = gridDim.x >> 3;              // 64
    const int logical = (p & 7) * cpx + (p >> 3);
    const int tok0 = (logical >> 1) * BM;
    const int e0   = (logical & 1) * BN;

    // ---- A staging geometry: thread owns 8 floats (row ar, k-group aq)
    const int ar = tid >> 2;          // 0..63
    const int aq = tid & 3;           // 0..3
    const float* xp = X + (size_t)(tok0 + ar) * KDIM + aq * 8;
    const int aoff = (aq << 9) + (((ar ^ (aq << 1)) & 63) << 3);   // within A level

    // ---- B staging geometry: 2 chunks/thread/level; linear LDS dest (gll),
    //      pre-permuted global source row.
    int bg[2], brow[2];
    {
        int i0 = tid;        bg[0] = i0 >> 7; brow[0] = (i0 & 127) ^ (bg[0] << 1);
        int i1 = 256 + tid;  bg[1] = i1 >> 7; brow[1] = (i1 & 127) ^ (bg[1] << 1);
    }

    // ---- compute-side LDS offsets (shorts)
    const int g = lane >> 4;          // k-group
    int aro[2], bro[4];
#pragma unroll
    for (int mf = 0; mf < 2; ++mf) {
        int r = wm * 32 + mf * 16 + (lane & 15);
        aro[mf] = (g << 9) + (((r ^ (g << 1)) & 63) << 3);
    }
#pragma unroll
    for (int nf = 0; nf < 4; ++nf) {
        int e = wn * 64 + nf * 16 + (lane & 15);
        bro[nf] = (g << 10) + (((e ^ (g << 1)) & 127) << 3);
    }

    auto stageB = [&](short* buf, int k0) {
        short* dstB = buf + 6144;
#pragma unroll
        for (int lev = 0; lev < 3; ++lev) {
            const short* src = (lev == 0) ? W1 : ((lev == 1) ? W2 : W3);
            load_lds16(src + (size_t)(e0 + brow[0]) * KDIM + k0 + (bg[0] << 3),
                       dstB + lev * 4096 + tid * 8);
            load_lds16(src + (size_t)(e0 + brow[1]) * KDIM + k0 + (bg[1] << 3),
                       dstB + lev * 4096 + (256 + tid) * 8);
        }
    };

    auto writeA = [&](short* buf, float4 a0, float4 a1) {
        bf16x8 s1, s2, s3;
        float v[8] = {a0.x, a0.y, a0.z, a0.w, a1.x, a1.y, a1.z, a1.w};
#pragma unroll
        for (int j = 0; j < 8; ++j) {
            short h1, h2, h3; split1(v[j], h1, h2, h3);
            s1[j] = h1; s2[j] = h2; s3[j] = h3;
        }
        *(bf16x8*)&buf[0 * 2048 + aoff] = s1;
        *(bf16x8*)&buf[1 * 2048 + aoff] = s2;
        *(bf16x8*)&buf[2 * 2048 + aoff] = s3;
    };

    f32x4 acc[2][4];
#pragma unroll
    for (int i = 0; i < 2; ++i)
#pragma unroll
        for (int j = 0; j < 4; ++j) acc[i][j] = f32x4{0.f, 0.f, 0.f, 0.f};

    auto compute = [&](const short* buf) {
        bf16x8 af[2][3], bfr[4][3];
#pragma unroll
        for (int mf = 0; mf < 2; ++mf)
#pragma unroll
            for (int lev = 0; lev < 3; ++lev)
                af[mf][lev] = *(const bf16x8*)&buf[lev * 2048 + aro[mf]];
#pragma unroll
        for (int nf = 0; nf < 4; ++nf)
#pragma unroll
            for (int lev = 0; lev < 3; ++lev)
                bfr[nf][lev] = *(const bf16x8*)&buf[6144 + lev * 4096 + bro[nf]];
#pragma unroll
        for (int mf = 0; mf < 2; ++mf)
#pragma unroll
            for (int nf = 0; nf < 4; ++nf) {
                f32x4 c = acc[mf][nf];
                c = __builtin_amdgcn_mfma_f32_16x16x32_bf16(af[mf][0], bfr[nf][0], c, 0, 0, 0);
                c = __builtin_amdgcn_mfma_f32_16x16x32_bf16(af[mf][0], bfr[nf][1], c, 0, 0, 0);
                c = __builtin_amdgcn_mfma_f32_16x16x32_bf16(af[mf][1], bfr[nf][0], c, 0, 0, 0);
                c = __builtin_amdgcn_mfma_f32_16x16x32_bf16(af[mf][1], bfr[nf][1], c, 0, 0, 0);
                c = __builtin_amdgcn_mfma_f32_16x16x32_bf16(af[mf][0], bfr[nf][2], c, 0, 0, 0);
                c = __builtin_amdgcn_mfma_f32_16x16x32_bf16(af[mf][2], bfr[nf][0], c, 0, 0, 0);
                acc[mf][nf] = c;
            }
    };

    // ---- prologue: stage step 0 into buffer 0
    stageB(lds, 0);
    {
        float4 a0 = *(const float4*)xp;
        float4 a1 = *(const float4*)(xp + 4);
        writeA(lds, a0, a1);
    }
    __syncthreads();

    // ---- main loop: prefetch ks+1 into nxt, compute cur, one barrier/step
    int buf = 0;
    for (int ks = 0; ks < NSTEP - 1; ++ks) {
        short* cur = lds + buf * BUFS;
        short* nxt = lds + (buf ^ 1) * BUFS;
        const float* xn = xp + (size_t)(ks + 1) * BK;
        float4 a0 = *(const float4*)xn;        // A prefetch -> regs (issued early)
        float4 a1 = *(const float4*)(xn + 4);
        stageB(nxt, (ks + 1) * BK);            // B prefetch -> LDS (async)
        compute(cur);
        writeA(nxt, a0, a1);
        __syncthreads();                       // drains B gll (issued 1 phase ago)
        buf ^= 1;
    }
    compute(lds + buf * BUFS);

    // ---- epilogue: sigmoid + bias -> scores
    // C/D layout: col(expert) = lane&15, row(token) = (lane>>4)*4 + v.
#pragma unroll
    for (int mf = 0; mf < 2; ++mf)
#pragma unroll
        for (int nf = 0; nf < 4; ++nf) {
            const int ec = e0 + wn * 64 + nf * 16 + (lane & 15);
            const float bv = Bias[ec];
#pragma unroll
            for (int v = 0; v < 4; ++v) {
                const int tr = tok0 + wm * 32 + mf * 16 + (lane >> 4) * 4 + v;
                S[(size_t)tr * E_EXPERTS + ec] = 1.0f / (1.0f + expf(-acc[mf][nf][v])) + bv;
            }
        }
}

// One wave per token: 256 scores, 4/lane; 8 rounds of butterfly argmax.
// Tie-break: higher value wins; equal value -> lower index (matches lax.top_k / np).
__global__ __launch_bounds__(256) void gate_topk(
    const float* __restrict__ S, float* __restrict__ outIdx,
    float* __restrict__ outW, int T) {
    const int wave = threadIdx.x >> 6;
    const int lane = threadIdx.x & 63;
    const int t    = blockIdx.x * 4 + wave;
    if (t >= T) return;

    const float* row = S + (size_t)t * E_EXPERTS;
    float v[4];
    int   idx[4];
#pragma unroll
    for (int j = 0; j < 4; ++j) {
        idx[j] = lane + 64 * j;
        v[j]   = row[idx[j]];
    }

    float tv[TOPK];
    int   ti[TOPK];
#pragma unroll
    for (int k = 0; k < TOPK; ++k) {
        float bv = v[0];
        int   bi = idx[0];
#pragma unroll
        for (int j = 1; j < 4; ++j)
            if (v[j] > bv) { bv = v[j]; bi = idx[j]; }
#pragma unroll
        for (int off = 1; off < 64; off <<= 1) {
            float ov = __shfl_xor(bv, off);
            int   oi = __shfl_xor(bi, off);
            if (ov > bv || (ov == bv && oi < bi)) { bv = ov; bi = oi; }
        }
        tv[k] = bv;
        ti[k] = bi;
#pragma unroll
        for (int j = 0; j < 4; ++j)
            if (idx[j] == bi) v[j] = -INFINITY;
    }

    float denom = 0.0f;
#pragma unroll
    for (int k = 0; k < TOPK; ++k) denom += tv[k];
    denom += 1e-20f;

#pragma unroll
    for (int k = 0; k < TOPK; ++k) {
        if (lane == k) {
            outIdx[(size_t)t * TOPK + k] = (float)ti[k];
            outW[(size_t)t * TOPK + k]   = (tv[k] / denom) * SCALE;
        }
    }
}

extern "C" void kernel_launch(void* const* d_in, const int* in_sizes, int n_in,
                              void* d_out, int out_size, void* d_ws, size_t ws_size,
                              hipStream_t stream) {
    const float* x    = (const float*)d_in[0];
    const float* w    = (const float*)d_in[1];
    const float* bias = (const float*)d_in[2];

    const int T = in_sizes[0] / KDIM;   // 16384

    float* S  = (float*)d_ws;                                        // [T][256] f32, 16 MiB
    short* W1 = (short*)((char*)d_ws + (size_t)T * E_EXPERTS * 4);   // 3 x 2 MiB bf16
    short* W2 = W1 + (size_t)E_EXPERTS * KDIM;
    short* W3 = W2 + (size_t)E_EXPERTS * KDIM;

    float* outIdx = (float*)d_out;                  // idx chunk (as float values)
    float* outW   = outIdx + (size_t)T * TOPK;      // weight chunk

    wsplit_kernel<<<(E_EXPERTS * KDIM / 4) / 256, 256, 0, stream>>>(w, W1, W2, W3);
    gate_gemm<<<(T / BM) * (E_EXPERTS / BN), NT, 0, stream>>>(x, W1, W2, W3, bias, S);
    gate_topk<<<T / 4, 256, 0, stream>>>(S, outIdx, outW, T);
}

// Round 6
// 269.293 us; speedup vs baseline: 1.5138x; 1.0877x over previous
//
#include <hip/hip_runtime.h>
#include <hip/hip_bf16.h>
#include <math.h>

// Gate: logits = x @ W^T ; scores = sigmoid(logits)+bias ; top-8 ; normalize *2.5
// T=16384, H=K=4096, E=256.
// fp32 GEMM via EXACT 3-way bf16 truncation split (x = h1+h2+h3 bit-exact),
// 6 cross products (11,12,21,22,13,31) -> rel error ~2^-24 (bf16 splits are
// never denormal -- f16 2-split failed in R5 via MFMA denormal flush).
// Round 6: A fully in registers; B-only single-buffered LDS (48 KiB) ->
// 3 blocks/CU; BK=64; A(k+1) reg-prefetch under compute; XCD pair-swizzle.

using bf16x4 = __attribute__((ext_vector_type(4))) short;
using bf16x8 = __attribute__((ext_vector_type(8))) short;
using f32x4  = __attribute__((ext_vector_type(4))) float;

constexpr int E_EXPERTS = 256;
constexpr int KDIM      = 4096;
constexpr int TOPK      = 8;
constexpr float SCALE   = 2.5f;

constexpr int BM = 64, BN = 128, BK = 64, NT = 256;
constexpr int NSTEP = KDIM / BK;   // 64
// LDS: B only, single buffer: 3 levels x [128 e][64 k] bf16 = 24576 shorts = 48 KiB.
// Row = 64 shorts (128 B) = 8 chunks of 8 bf16. Physical chunk pc of row e holds
// logical k-chunk pc ^ (e&7): a 16-lane MFMA group's ds_read_b128 then spreads
// over 8 chunk slots -> 2 lanes/bank = free. gll dest stays LINEAR; the global
// source column is pre-permuted with the same XOR (both-sides rule).

__device__ __forceinline__ void load_lds16(const short* g, short* l) {
    auto gp = (const __attribute__((address_space(1))) short*)g;
    auto lp = (__attribute__((address_space(3))) short*)(uintptr_t)l;
    __builtin_amdgcn_global_load_lds(gp, lp, 16, 0, 0);
}

// Exact truncation split: x == bf16(h1)+bf16(h2)+bf16(h3) (normal fp32).
__device__ __forceinline__ void split1(float x, short& h1, short& h2, short& h3) {
    unsigned u = __float_as_uint(x);
    h1 = (short)(u >> 16);
    float r1 = x - __uint_as_float(u & 0xFFFF0000u);
    unsigned u1 = __float_as_uint(r1);
    h2 = (short)(u1 >> 16);
    float r2 = r1 - __uint_as_float(u1 & 0xFFFF0000u);
    h3 = (short)(__float_as_uint(r2) >> 16);
}

__global__ void wsplit_kernel(const float* __restrict__ W, short* __restrict__ W1,
                              short* __restrict__ W2, short* __restrict__ W3) {
    int i = blockIdx.x * 256 + threadIdx.x;   // float4 index
    float4 w = ((const float4*)W)[i];
    bf16x4 s1, s2, s3;
    short a, b, c;
    split1(w.x, a, b, c); s1.x = a; s2.x = b; s3.x = c;
    split1(w.y, a, b, c); s1.y = a; s2.y = b; s3.y = c;
    split1(w.z, a, b, c); s1.z = a; s2.z = b; s3.z = c;
    split1(w.w, a, b, c); s1.w = a; s2.w = b; s3.w = c;
    ((bf16x4*)W1)[i] = s1;
    ((bf16x4*)W2)[i] = s2;
    ((bf16x4*)W3)[i] = s3;
}

__global__ __launch_bounds__(NT, 3) void gate_gemm(
    const float* __restrict__ X,
    const short* __restrict__ W1, const short* __restrict__ W2, const short* __restrict__ W3,
    const float* __restrict__ Bias, float* __restrict__ S) {
    __shared__ short lds[3 * 8192];   // 48 KiB -> 3 blocks/CU

    const int tid  = threadIdx.x;
    const int lane = tid & 63;
    const int w    = tid >> 6;        // wave 0..3
    const int wm   = w >> 1;          // 0..1 : 32-token half
    const int wn   = w & 1;           // 0..1 : 64-expert half
    const int g    = lane >> 4;       // k-chunk within 32-k group

    // XCD swizzle: the two expert-halves of a token tile are logically adjacent
    // -> same XCD -> X L2-reuse.
    const int p       = blockIdx.x;
    const int cpx     = gridDim.x >> 3;              // 64
    const int logical = (p & 7) * cpx + (p >> 3);
    const int tok0 = (logical >> 1) * BM;
    const int e0   = (logical & 1) * BN;

    // ---- A (in-register): frag (mf,ks2): row = wm*32+mf*16+(lane&15),
    //      k = ks*64 + ks2*32 + g*8 .. +7  (8 consecutive fp32 per lane).
    const float* xa[2][2];
#pragma unroll
    for (int mf = 0; mf < 2; ++mf)
#pragma unroll
        for (int ks2 = 0; ks2 < 2; ++ks2)
            xa[mf][ks2] = X + (size_t)(tok0 + wm * 32 + mf * 16 + (lane & 15)) * KDIM
                            + ks2 * 32 + g * 8;

    // ---- B staging: 1024 16B-units per level, 4 per thread per level.
    int bsrc[4], bdst[4];   // short offsets (k0, lev added at use)
#pragma unroll
    for (int j = 0; j < 4; ++j) {
        int f = j * 256 + tid;
        int e = f >> 3, pc = f & 7;
        int c = pc ^ (e & 7);
        bsrc[j] = (e0 + e) * KDIM + c * 8;
        bdst[j] = f * 8;
    }

    // ---- B compute-side read offsets (shorts, within level region)
    int bro[4][2];   // [nf][ks2]
#pragma unroll
    for (int nf = 0; nf < 4; ++nf) {
        int e = wn * 64 + nf * 16 + (lane & 15);
#pragma unroll
        for (int ks2 = 0; ks2 < 2; ++ks2)
            bro[nf][ks2] = e * 64 + (((ks2 << 2) + g) ^ (e & 7)) * 8;
    }

    auto stage = [&](int k0) {
#pragma unroll
        for (int j = 0; j < 4; ++j) {
            load_lds16(W1 + (size_t)bsrc[j] + k0, &lds[0 * 8192 + bdst[j]]);
            load_lds16(W2 + (size_t)bsrc[j] + k0, &lds[1 * 8192 + bdst[j]]);
            load_lds16(W3 + (size_t)bsrc[j] + k0, &lds[2 * 8192 + bdst[j]]);
        }
    };

    float4 raw[2][2][2];   // [mf][ks2][half]
    auto loadA = [&](int ks) {
#pragma unroll
        for (int mf = 0; mf < 2; ++mf)
#pragma unroll
            for (int ks2 = 0; ks2 < 2; ++ks2) {
                const float* s = xa[mf][ks2] + (size_t)ks * BK;
                raw[mf][ks2][0] = *(const float4*)s;
                raw[mf][ks2][1] = *(const float4*)(s + 4);
            }
    };

    f32x4 acc[2][4];
#pragma unroll
    for (int i = 0; i < 2; ++i)
#pragma unroll
        for (int j = 0; j < 4; ++j) acc[i][j] = f32x4{0.f, 0.f, 0.f, 0.f};

    loadA(0);

    for (int ks = 0; ks < NSTEP; ++ks) {
        stage(ks * BK);   // 12 gll into the single buffer (prev readers done)

        // split current A (raw) into 3 bf16 levels, lane-local
        bf16x8 fa[2][2][3];   // [mf][ks2][lev]
#pragma unroll
        for (int mf = 0; mf < 2; ++mf)
#pragma unroll
            for (int ks2 = 0; ks2 < 2; ++ks2) {
                float v[8] = {raw[mf][ks2][0].x, raw[mf][ks2][0].y,
                              raw[mf][ks2][0].z, raw[mf][ks2][0].w,
                              raw[mf][ks2][1].x, raw[mf][ks2][1].y,
                              raw[mf][ks2][1].z, raw[mf][ks2][1].w};
                bf16x8 s1, s2, s3;
#pragma unroll
                for (int j = 0; j < 8; ++j) {
                    short h1, h2, h3; split1(v[j], h1, h2, h3);
                    s1[j] = h1; s2[j] = h2; s3[j] = h3;
                }
                fa[mf][ks2][0] = s1; fa[mf][ks2][1] = s2; fa[mf][ks2][2] = s3;
            }

        if (ks + 1 < NSTEP) loadA(ks + 1);   // A prefetch; latency hides under MFMA

        __syncthreads();   // drains gll -> B tile ready

#pragma unroll
        for (int nf = 0; nf < 4; ++nf) {
            bf16x8 fb[3][2];   // [lev][ks2]
#pragma unroll
            for (int lev = 0; lev < 3; ++lev)
#pragma unroll
                for (int ks2 = 0; ks2 < 2; ++ks2)
                    fb[lev][ks2] = *(const bf16x8*)&lds[lev * 8192 + bro[nf][ks2]];
#pragma unroll
            for (int mf = 0; mf < 2; ++mf) {
                f32x4 c = acc[mf][nf];
#pragma unroll
                for (int ks2 = 0; ks2 < 2; ++ks2) {
                    c = __builtin_amdgcn_mfma_f32_16x16x32_bf16(fa[mf][ks2][0], fb[0][ks2], c, 0, 0, 0);
                    c = __builtin_amdgcn_mfma_f32_16x16x32_bf16(fa[mf][ks2][0], fb[1][ks2], c, 0, 0, 0);
                    c = __builtin_amdgcn_mfma_f32_16x16x32_bf16(fa[mf][ks2][1], fb[0][ks2], c, 0, 0, 0);
                    c = __builtin_amdgcn_mfma_f32_16x16x32_bf16(fa[mf][ks2][1], fb[1][ks2], c, 0, 0, 0);
                    c = __builtin_amdgcn_mfma_f32_16x16x32_bf16(fa[mf][ks2][0], fb[2][ks2], c, 0, 0, 0);
                    c = __builtin_amdgcn_mfma_f32_16x16x32_bf16(fa[mf][ks2][2], fb[0][ks2], c, 0, 0, 0);
                }
                acc[mf][nf] = c;
            }
        }
        __syncthreads();   // all waves done reading before next stage overwrites
    }

    // ---- epilogue: sigmoid + bias -> scores
    // C/D layout: col(expert) = lane&15, row(token) = (lane>>4)*4 + v.
#pragma unroll
    for (int mf = 0; mf < 2; ++mf)
#pragma unroll
        for (int nf = 0; nf < 4; ++nf) {
            const int ec = e0 + wn * 64 + nf * 16 + (lane & 15);
            const float bv = Bias[ec];
#pragma unroll
            for (int v = 0; v < 4; ++v) {
                const int tr = tok0 + wm * 32 + mf * 16 + (lane >> 4) * 4 + v;
                S[(size_t)tr * E_EXPERTS + ec] = 1.0f / (1.0f + expf(-acc[mf][nf][v])) + bv;
            }
        }
}

// One wave per token: 256 scores, 4/lane; 8 rounds of butterfly argmax.
// Tie-break: higher value wins; equal value -> lower index (matches lax.top_k / np).
__global__ __launch_bounds__(256) void gate_topk(
    const float* __restrict__ S, float* __restrict__ outIdx,
    float* __restrict__ outW, int T) {
    const int wave = threadIdx.x >> 6;
    const int lane = threadIdx.x & 63;
    const int t    = blockIdx.x * 4 + wave;
    if (t >= T) return;

    const float* row = S + (size_t)t * E_EXPERTS;
    float v[4];
    int   idx[4];
#pragma unroll
    for (int j = 0; j < 4; ++j) {
        idx[j] = lane + 64 * j;
        v[j]   = row[idx[j]];
    }

    float tv[TOPK];
    int   ti[TOPK];
#pragma unroll
    for (int k = 0; k < TOPK; ++k) {
        float bv = v[0];
        int   bi = idx[0];
#pragma unroll
        for (int j = 1; j < 4; ++j)
            if (v[j] > bv) { bv = v[j]; bi = idx[j]; }
#pragma unroll
        for (int off = 1; off < 64; off <<= 1) {
            float ov = __shfl_xor(bv, off);
            int   oi = __shfl_xor(bi, off);
            if (ov > bv || (ov == bv && oi < bi)) { bv = ov; bi = oi; }
        }
        tv[k] = bv;
        ti[k] = bi;
#pragma unroll
        for (int j = 0; j < 4; ++j)
            if (idx[j] == bi) v[j] = -INFINITY;
    }

    float denom = 0.0f;
#pragma unroll
    for (int k = 0; k < TOPK; ++k) denom += tv[k];
    denom += 1e-20f;

#pragma unroll
    for (int k = 0; k < TOPK; ++k) {
        if (lane == k) {
            outIdx[(size_t)t * TOPK + k] = (float)ti[k];
            outW[(size_t)t * TOPK + k]   = (tv[k] / denom) * SCALE;
        }
    }
}

extern "C" void kernel_launch(void* const* d_in, const int* in_sizes, int n_in,
                              void* d_out, int out_size, void* d_ws, size_t ws_size,
                              hipStream_t stream) {
    const float* x    = (const float*)d_in[0];
    const float* w    = (const float*)d_in[1];
    const float* bias = (const float*)d_in[2];

    const int T = in_sizes[0] / KDIM;   // 16384

    float* S  = (float*)d_ws;                                        // [T][256] f32, 16 MiB
    short* W1 = (short*)((char*)d_ws + (size_t)T * E_EXPERTS * 4);   // 3 x 2 MiB bf16
    short* W2 = W1 + (size_t)E_EXPERTS * KDIM;
    short* W3 = W2 + (size_t)E_EXPERTS * KDIM;

    float* outIdx = (float*)d_out;                  // idx chunk (as float values)
    float* outW   = outIdx + (size_t)T * TOPK;      // weight chunk

    wsplit_kernel<<<(E_EXPERTS * KDIM / 4) / 256, 256, 0, stream>>>(w, W1, W2, W3);
    gate_gemm<<<(T / BM) * (E_EXPERTS / BN), NT, 0, stream>>>(x, W1, W2, W3, bias, S);
    gate_topk<<<T / 4, 256, 0, stream>>>(S, outIdx, outW, T);
}